// Round 1
// baseline (630.578 us; speedup 1.0000x reference)
//
#include <hip/hip_runtime.h>

#define LR        0.01f
#define WD        1e-4f
// log2(0.9)
#define L2MOM     (-0.15200309344507500f)

// K1: scatter gradient values + NaN flags into the output buffers.
// out_mom[idx] <- grad value (temporary storage, finalized by K2)
// out_lu[idx]  <- NaN (flag: "this position is updated")
// NaN never collides with legitimate out_lu content (old lu in [0,9],
// poison 0xAAAAAAAA = -3e-13, zero-init, or our previous finite outputs),
// so no init pass is required and replays are deterministic.
__global__ void sgd_scatter_mark(const int* __restrict__ idx,
                                 const float* __restrict__ gv,
                                 float* __restrict__ out_mom,
                                 float* __restrict__ out_lu,
                                 int nnz) {
    int j = blockIdx.x * blockDim.x + threadIdx.x;
    if (j >= nnz) return;
    int i = idx[j];
    out_mom[i] = gv[j];
    out_lu[i]  = __int_as_float(0x7fc00000); // quiet NaN
}

// K2: one dense vectorized pass over all P elements.
// flagged:   g = g_raw + WD*p; mf = 0.9^(iter-lu); bn = mf*m + g
//            out_param = p - LR*bn; out_mom = bn; out_lu = iter
// unflagged: plain copy (param, mom, float(lu))
__global__ void sgd_dense(const float* __restrict__ param,
                          const float* __restrict__ mom,
                          const int*   __restrict__ lu,
                          const int*   __restrict__ iter_p,
                          float* __restrict__ out_param,
                          float* __restrict__ out_mom,
                          float* __restrict__ out_lu,
                          int n) {
    const int   it  = *iter_p;
    const float itf = (float)it;

    long long tid    = (long long)blockIdx.x * blockDim.x + threadIdx.x;
    long long stride = (long long)gridDim.x * blockDim.x;
    const int n4 = n >> 2;

    for (long long t = tid; t < n4; t += stride) {
        const int i = (int)(t << 2);
        const float4 p  = *reinterpret_cast<const float4*>(param   + i);
        const float4 m  = *reinterpret_cast<const float4*>(mom     + i);
        const int4   l  = *reinterpret_cast<const int4*>(lu        + i);
        const float4 fl = *reinterpret_cast<const float4*>(out_lu  + i);
        const float4 gr = *reinterpret_cast<const float4*>(out_mom + i);
        float4 op, om, ol;

#define SGD_COMP(c)                                                        \
        {                                                                  \
            const bool  upd = (fl.c != fl.c); /* isnan -> flagged */       \
            const float gg  = gr.c + WD * p.c;                             \
            const float mf  = exp2f((float)(it - l.c) * L2MOM);            \
            const float bn  = fmaf(mf, m.c, gg);                           \
            om.c = upd ? bn : m.c;                                         \
            op.c = upd ? fmaf(-LR, bn, p.c) : p.c;                         \
            ol.c = upd ? itf : (float)l.c;                                 \
        }
        SGD_COMP(x)
        SGD_COMP(y)
        SGD_COMP(z)
        SGD_COMP(w)
#undef SGD_COMP

        *reinterpret_cast<float4*>(out_param + i) = op;
        *reinterpret_cast<float4*>(out_mom   + i) = om;
        *reinterpret_cast<float4*>(out_lu    + i) = ol;
    }

    // scalar tail (P=50M is divisible by 4, but stay general)
    if (tid == 0) {
        for (int i = (n4 << 2); i < n; ++i) {
            const float flv = out_lu[i];
            const bool  upd = (flv != flv);
            const float gg  = out_mom[i] + WD * param[i];
            const float mf  = exp2f((float)(it - lu[i]) * L2MOM);
            const float bn  = fmaf(mf, mom[i], gg);
            out_mom[i]   = upd ? bn : mom[i];
            out_param[i] = upd ? fmaf(-LR, bn, param[i]) : param[i];
            out_lu[i]    = upd ? itf : (float)lu[i];
        }
    }
}

extern "C" void kernel_launch(void* const* d_in, const int* in_sizes, int n_in,
                              void* d_out, int out_size, void* d_ws, size_t ws_size,
                              hipStream_t stream) {
    const float* param = (const float*)d_in[0];
    const float* gv    = (const float*)d_in[1];
    const int*   gidx  = (const int*)d_in[2];
    const float* mom   = (const float*)d_in[3];
    const int*   lu    = (const int*)d_in[4];
    const int*   iter  = (const int*)d_in[5];

    const int Pn  = in_sizes[0];
    const int nnz = in_sizes[1];

    float* out_param = (float*)d_out;
    float* out_mom   = out_param + Pn;
    float* out_lu    = out_mom + Pn;

    // K1: scatter marks (must complete before K2 reads flags; same stream
    // serializes the two kernels).
    const int b1 = (nnz + 255) / 256;
    sgd_scatter_mark<<<b1, 256, 0, stream>>>(gidx, gv, out_mom, out_lu, nnz);

    // K2: dense vectorized pass, grid-stride.
    const int n4 = Pn >> 2;
    int b2 = (n4 + 255) / 256;
    if (b2 > 4096) b2 = 4096;
    sgd_dense<<<b2, 256, 0, stream>>>(param, mom, lu, iter,
                                      out_param, out_mom, out_lu, Pn);
}

// Round 2
// 402.124 us; speedup vs baseline: 1.5681x; 1.5681x over previous
//
#include <hip/hip_runtime.h>

#define LR        0.01f
#define WD        1e-4f
// log2(0.9)
#define L2MOM     (-0.15200309344507500f)

typedef float f32x4 __attribute__((ext_vector_type(4)));
typedef int   i32x4 __attribute__((ext_vector_type(4)));

// ======================= mask path (preferred) =======================

// K1: scatter gradient values into out_mom (dense temp) and set a bit per
// touched element in the workspace bitmask (memset to 0 each launch).
__global__ void sgd_scatter_mask(const int* __restrict__ idx,
                                 const float* __restrict__ gv,
                                 float* __restrict__ gdense,
                                 unsigned int* __restrict__ mask,
                                 int nnz) {
    int j = blockIdx.x * blockDim.x + threadIdx.x;
    if (j >= nnz) return;
    int i = idx[j];
    gdense[i] = gv[j];
    atomicOr(&mask[i >> 5], 1u << (i & 31));
}

__device__ __forceinline__ void sgd_compute4(const f32x4 p, const f32x4 m,
                                             const i32x4 l, const f32x4 g,
                                             unsigned nib, int it, float itf,
                                             f32x4& op, f32x4& om, f32x4& ol) {
#pragma unroll
    for (int c = 0; c < 4; ++c) {
        const bool  upd = (nib >> c) & 1u;
        const float gg  = g[c] + WD * p[c];
        const float mf  = exp2f((float)(it - l[c]) * L2MOM);
        const float bn  = fmaf(mf, m[c], gg);
        om[c] = upd ? bn : m[c];
        op[c] = upd ? fmaf(-LR, bn, p[c]) : p[c];
        ol[c] = upd ? itf : (float)l[c];
    }
}

// K2: one-shot dense pass, 2 float4 per thread (block-strided pair so each
// load instruction is a contiguous 1KB wave access). No grid-stride loop:
// all loads issue up front for maximum MLP.
__global__ void __launch_bounds__(256)
sgd_dense_mask(const f32x4* __restrict__ param,
               const f32x4* __restrict__ mom,
               const i32x4* __restrict__ lu,
               const f32x4* __restrict__ gdense,
               const unsigned int* __restrict__ mask,
               const int* __restrict__ iter_p,
               f32x4* __restrict__ out_param,
               f32x4* __restrict__ out_mom,
               f32x4* __restrict__ out_lu,
               int n4, int n) {
    const int   it  = *iter_p;
    const float itf = (float)it;

    const int v0 = blockIdx.x * (blockDim.x * 2) + threadIdx.x;
    const int v1 = v0 + blockDim.x;

    if (v1 < n4) {
        // issue all loads before any compute
        const f32x4 p0 = __builtin_nontemporal_load(&param[v0]);
        const f32x4 p1 = __builtin_nontemporal_load(&param[v1]);
        const f32x4 m0 = __builtin_nontemporal_load(&mom[v0]);
        const f32x4 m1 = __builtin_nontemporal_load(&mom[v1]);
        const i32x4 l0 = __builtin_nontemporal_load(&lu[v0]);
        const i32x4 l1 = __builtin_nontemporal_load(&lu[v1]);
        const f32x4 g0 = gdense[v0];
        const f32x4 g1 = gdense[v1];
        const unsigned w0 = mask[v0 >> 3];
        const unsigned w1 = mask[v1 >> 3];

        const unsigned nib0 = (w0 >> ((v0 & 7) * 4)) & 0xFu;
        const unsigned nib1 = (w1 >> ((v1 & 7) * 4)) & 0xFu;

        f32x4 op0, om0, ol0, op1, om1, ol1;
        sgd_compute4(p0, m0, l0, g0, nib0, it, itf, op0, om0, ol0);
        sgd_compute4(p1, m1, l1, g1, nib1, it, itf, op1, om1, ol1);

        __builtin_nontemporal_store(op0, &out_param[v0]);
        __builtin_nontemporal_store(op1, &out_param[v1]);
        __builtin_nontemporal_store(om0, &out_mom[v0]);
        __builtin_nontemporal_store(om1, &out_mom[v1]);
        __builtin_nontemporal_store(ol0, &out_lu[v0]);
        __builtin_nontemporal_store(ol1, &out_lu[v1]);
    } else if (v0 < n4) {
        const f32x4 p0 = __builtin_nontemporal_load(&param[v0]);
        const f32x4 m0 = __builtin_nontemporal_load(&mom[v0]);
        const i32x4 l0 = __builtin_nontemporal_load(&lu[v0]);
        const f32x4 g0 = gdense[v0];
        const unsigned w0   = mask[v0 >> 3];
        const unsigned nib0 = (w0 >> ((v0 & 7) * 4)) & 0xFu;
        f32x4 op0, om0, ol0;
        sgd_compute4(p0, m0, l0, g0, nib0, it, itf, op0, om0, ol0);
        __builtin_nontemporal_store(op0, &out_param[v0]);
        __builtin_nontemporal_store(om0, &out_mom[v0]);
        __builtin_nontemporal_store(ol0, &out_lu[v0]);
    }

    // scalar tail for n % 4 != 0 (not hit for P=50M, kept for generality)
    if (v0 == 0) {
        const float* paramS = (const float*)param;
        const float* momS   = (const float*)mom;
        const int*   luS    = (const int*)lu;
        const float* gS     = (const float*)gdense;
        float* opS = (float*)out_param;
        float* omS = (float*)out_mom;
        float* olS = (float*)out_lu;
        for (int i = n4 << 2; i < n; ++i) {
            const bool  upd = (mask[i >> 5] >> (i & 31)) & 1u;
            const float gg  = gS[i] + WD * paramS[i];
            const float mf  = exp2f((float)(it - luS[i]) * L2MOM);
            const float bn  = fmaf(mf, momS[i], gg);
            omS[i] = upd ? bn : momS[i];
            opS[i] = upd ? fmaf(-LR, bn, paramS[i]) : paramS[i];
            olS[i] = upd ? itf : (float)luS[i];
        }
    }
}

// ======================= fallback path (ws too small) =======================

__global__ void sgd_scatter_nan(const int* __restrict__ idx,
                                const float* __restrict__ gv,
                                float* __restrict__ out_mom,
                                float* __restrict__ out_lu,
                                int nnz) {
    int j = blockIdx.x * blockDim.x + threadIdx.x;
    if (j >= nnz) return;
    int i = idx[j];
    out_mom[i] = gv[j];
    out_lu[i]  = __int_as_float(0x7fc00000);
}

__global__ void sgd_dense_nan(const float* __restrict__ param,
                              const float* __restrict__ mom,
                              const int*   __restrict__ lu,
                              const int*   __restrict__ iter_p,
                              float* __restrict__ out_param,
                              float* __restrict__ out_mom,
                              float* __restrict__ out_lu,
                              int n) {
    const int   it  = *iter_p;
    const float itf = (float)it;
    long long tid    = (long long)blockIdx.x * blockDim.x + threadIdx.x;
    long long stride = (long long)gridDim.x * blockDim.x;
    const int n4 = n >> 2;
    for (long long t = tid; t < n4; t += stride) {
        const int i = (int)(t << 2);
        const float4 p  = *reinterpret_cast<const float4*>(param   + i);
        const float4 m  = *reinterpret_cast<const float4*>(mom     + i);
        const int4   l  = *reinterpret_cast<const int4*>(lu        + i);
        const float4 fl = *reinterpret_cast<const float4*>(out_lu  + i);
        const float4 gr = *reinterpret_cast<const float4*>(out_mom + i);
        float4 op, om, ol;
#define SGD_COMP(c)                                                        \
        {                                                                  \
            const bool  upd = (fl.c != fl.c);                              \
            const float gg  = gr.c + WD * p.c;                             \
            const float mf  = exp2f((float)(it - l.c) * L2MOM);            \
            const float bn  = fmaf(mf, m.c, gg);                           \
            om.c = upd ? bn : m.c;                                         \
            op.c = upd ? fmaf(-LR, bn, p.c) : p.c;                         \
            ol.c = upd ? itf : (float)l.c;                                 \
        }
        SGD_COMP(x) SGD_COMP(y) SGD_COMP(z) SGD_COMP(w)
#undef SGD_COMP
        *reinterpret_cast<float4*>(out_param + i) = op;
        *reinterpret_cast<float4*>(out_mom   + i) = om;
        *reinterpret_cast<float4*>(out_lu    + i) = ol;
    }
    if (tid == 0) {
        for (int i = (n4 << 2); i < n; ++i) {
            const float flv = out_lu[i];
            const bool  upd = (flv != flv);
            const float gg  = out_mom[i] + WD * param[i];
            const float mf  = exp2f((float)(it - lu[i]) * L2MOM);
            const float bn  = fmaf(mf, mom[i], gg);
            out_mom[i]   = upd ? bn : mom[i];
            out_param[i] = upd ? fmaf(-LR, bn, param[i]) : param[i];
            out_lu[i]    = upd ? itf : (float)lu[i];
        }
    }
}

// ======================= launch =======================

extern "C" void kernel_launch(void* const* d_in, const int* in_sizes, int n_in,
                              void* d_out, int out_size, void* d_ws, size_t ws_size,
                              hipStream_t stream) {
    const float* param = (const float*)d_in[0];
    const float* gv    = (const float*)d_in[1];
    const int*   gidx  = (const int*)d_in[2];
    const float* mom   = (const float*)d_in[3];
    const int*   lu    = (const int*)d_in[4];
    const int*   iter  = (const int*)d_in[5];

    const int Pn  = in_sizes[0];
    const int nnz = in_sizes[1];

    float* out_param = (float*)d_out;
    float* out_mom   = out_param + Pn;
    float* out_lu    = out_mom + Pn;

    const int    maskWords = (Pn + 31) >> 5;
    const size_t maskBytes = (size_t)maskWords * sizeof(unsigned int);

    if (ws_size >= maskBytes) {
        unsigned int* mask = (unsigned int*)d_ws;
        hipMemsetAsync(mask, 0, maskBytes, stream);

        const int b1 = (nnz + 255) / 256;
        sgd_scatter_mask<<<b1, 256, 0, stream>>>(gidx, gv, out_mom, mask, nnz);

        const int n4 = Pn >> 2;
        const int b2 = (n4 + 511) / 512;   // 512 float4 per block (2 per thread)
        sgd_dense_mask<<<b2, 256, 0, stream>>>(
            (const f32x4*)param, (const f32x4*)mom, (const i32x4*)lu,
            (const f32x4*)out_mom, mask, iter,
            (f32x4*)out_param, (f32x4*)out_mom, (f32x4*)out_lu, n4, Pn);
    } else {
        const int b1 = (nnz + 255) / 256;
        sgd_scatter_nan<<<b1, 256, 0, stream>>>(gidx, gv, out_mom, out_lu, nnz);
        const int n4 = Pn >> 2;
        int b2 = (n4 + 255) / 256;
        if (b2 > 4096) b2 = 4096;
        sgd_dense_nan<<<b2, 256, 0, stream>>>(param, mom, lu, iter,
                                              out_param, out_mom, out_lu, Pn);
    }
}